// Round 12
// baseline (622.779 us; speedup 1.0000x reference)
//
#include <hip/hip_runtime.h>
#include <hip/hip_bf16.h>

#define NE   64
#define NH   1024
#define NF   2816
#define TPE  64
#define PITCH 72      // x/A LDS pitch (validated)
#define WP   1032     // w-panel LDS pitch in ushorts (2064B rows; read=8-cy min)

typedef __attribute__((ext_vector_type(8))) short bf16x8;
typedef __attribute__((ext_vector_type(4))) float f32x4;

__device__ __forceinline__ ushort f2bf(float f) {
    union { float f; unsigned u; } v; v.f = f;
    unsigned r = v.u + 0x7fffu + ((v.u >> 16) & 1u);
    return (ushort)(r >> 16);
}

__device__ __forceinline__ float bf2f(ushort u) {
    union { unsigned u; float f; } v; v.u = ((unsigned)u) << 16;
    return v.f;
}

__device__ __forceinline__ bf16x8 cvt8(f32x4 lo, f32x4 hi) {
    bf16x8 r;
    #pragma unroll
    for (int j = 0; j < 4; ++j) {
        r[j]     = (short)f2bf(lo[j]);
        r[4 + j] = (short)f2bf(hi[j]);
    }
    return r;
}

// ---------------- Kernel 0: x (f32) -> xb (bf16), one pass -----------------
__global__ __launch_bounds__(256)
void xcast(const float* __restrict__ x, ushort* __restrict__ xb) {
    const int i = blockIdx.x * 256 + threadIdx.x;   // 8 elems per thread
    const f32x4 a = *(const f32x4*)(x + (size_t)i * 8);
    const f32x4 b = *(const f32x4*)(x + (size_t)i * 8 + 4);
    *(bf16x8*)(xb + (size_t)i * 8) = cvt8(a, b);
}

// ---- Kernel 1a/1b: x @ w^T with ONE-VISIT-PER-ROW weight streaming ----------
// DRAM-row-locality test on the clean R11 chassis. Per f-quarter phase:
// stage [16 f-rows x FULL K] weight panel — each 4KB row read ONCE,
// contiguously (1KB per wave instruction) — then 16 k-chunks of LDS-only MFMA
// against an 8KB x-tile restaged from L3-hot xb. grid (44,64); 42.2KB LDS ->
// 3 blocks/CU anti-phase.
// GATE=0: outp = x@w^T (bf16).  GATE=1: outp = silu(h1in) * (x@w^T) (bf16).
template <int GATE>
__global__ __launch_bounds__(256, 3)
void k1_mm(const ushort* __restrict__ xb,
           const float* __restrict__ w,
           const ushort* __restrict__ h1in,
           ushort* __restrict__ outp) {
    __shared__ ushort lW[16 * WP];       // 33 KB: 16 f-rows x K=1024 bf16
    __shared__ ushort lX[64 * PITCH];    // 9.2 KB: 64 tokens x 64 k bf16

    const int jt   = blockIdx.x;               // ff 64-tile (0..43)
    const int e    = blockIdx.y;               // expert
    const int tid  = threadIdx.x;
    const int lane = tid & 63;
    const int wid  = tid >> 6;
    const int m15  = lane & 15;
    const int hi   = lane >> 4;
    const int mrow = wid * 16 + m15;

    const ushort* A = xb + (size_t)e * TPE * NH;                     // [64][1024]
    const float*  B = w  + ((size_t)e * NF + (size_t)jt * 64) * NH;  // [64][1024]

    for (int fq = 0; fq < 4; ++fq) {           // four 16-row f-quarters
        __syncthreads();                        // prev phase's lW readers done
        // ---- stage w-panel: 16 rows x 4KB, each row ONE contiguous pass.
        // wave wid reads rows wid*4..wid*4+3; per row 4x (64 lanes x 16B = 1KB).
        #pragma unroll
        for (int r = 0; r < 4; ++r) {
            const int row = wid * 4 + r;
            const float* src = B + ((size_t)(fq * 16 + row)) * NH;
            #pragma unroll
            for (int i = 0; i < 4; ++i) {
                const f32x4 v0 = *(const f32x4*)(src + i * 256 + lane * 4);
                ushort4 u;
                u.x = f2bf(v0[0]); u.y = f2bf(v0[1]); u.z = f2bf(v0[2]); u.w = f2bf(v0[3]);
                *(ushort4*)(&lW[row * WP + i * 256 + lane * 4]) = u;
            }
        }

        f32x4 acc = f32x4{0.f, 0.f, 0.f, 0.f};

        for (int kc = 0; kc < 16; ++kc) {       // k-chunks of 64
            __syncthreads();                     // prev lX readers done; lW published (kc=0)
            // x-tile stage (R11-validated): 2 x b128 per thread from bf16 xb
            #pragma unroll
            for (int r = 0; r < 2; ++r) {
                const int q   = tid + r * 256;
                const int row = q >> 3;
                const int k8  = (q & 7) * 8;
                *(bf16x8*)(&lX[row * PITCH + k8]) =
                    *(const bf16x8*)(A + (size_t)row * NH + kc * 64 + k8);
            }
            __syncthreads();                     // tile staged

            #pragma unroll
            for (int ks = 0; ks < 2; ++ks) {
                const int ko = ks * 32 + hi * 8;
                const bf16x8 af = *(const bf16x8*)(&lX[mrow * PITCH + ko]);
                const bf16x8 bw = *(const bf16x8*)(&lW[m15 * WP + kc * 64 + ko]);
                acc = __builtin_amdgcn_mfma_f32_16x16x32_bf16(af, bw, acc, 0, 0, 0);
            }
        }

        // ---- per-phase epilogue (R11-validated indices). col=f, row=token.
        #pragma unroll
        for (int i = 0; i < 4; ++i) {
            const int row = wid * 16 + hi * 4 + i;
            const int col = jt * 64 + fq * 16 + m15;
            const size_t idx = ((size_t)e * TPE + row) * NF + col;
            if (GATE) {
                const float h1v = bf2f(h1in[idx]);          // L3-hot
                const float h3v = acc[i];
                const float s   = (h1v / (1.f + __expf(-h1v))) * h3v;
                outp[idx] = f2bf(s);
            } else {
                outp[idx] = f2bf(acc[i]);
            }
        }
    }
}

// ---------------- Kernel 2: out = gated @ w2 (per expert), fp32 out ------------
// (unchanged — single co-swept weight stream at ~7.1 TB/s; at roofline)
__global__ __launch_bounds__(256, 2)
void k2_down(const ushort* __restrict__ g,
             const float* __restrict__ w2,
             float* __restrict__ out) {
    __shared__ ushort lA[64 * PITCH];
    __shared__ ushort lB[64 * PITCH];

    const int jt   = blockIdx.x;
    const int e    = blockIdx.y;
    const int tid  = threadIdx.x;
    const int lane = tid & 63;
    const int wid  = tid >> 6;

    const ushort* A = g  + (size_t)e * TPE * NF;
    const float*  B = w2 + (size_t)e * NF * NH + (size_t)jt * 64;
    float* O = out + (size_t)e * TPE * NH + (size_t)jt * 64;

    f32x4 acc[4];
    for (int nf = 0; nf < 4; ++nf) acc[nf] = f32x4{0.f, 0.f, 0.f, 0.f};

    for (int kt = 0; kt < NF / 64; ++kt) {   // 44 iters
        __syncthreads();
        #pragma unroll
        for (int r = 0; r < 2; ++r) {
            const int q   = tid + r * 256;
            const int row = q >> 3;
            const int k8  = (q & 7) * 8;
            *(bf16x8*)(&lA[row * PITCH + k8]) =
                *(const bf16x8*)(A + (size_t)row * NF + kt * 64 + k8);
        }
        {
            const int n  = tid & 63;
            const int kq = (tid >> 6) * 4;
            #pragma unroll
            for (int r = 0; r < 4; ++r) {
                const int ks = kq + r * 16;
                const size_t base = (size_t)(kt * 64 + ks) * NH + n;
                const float f0 = B[base];
                const float f1 = B[base + NH];
                const float f2 = B[base + 2 * (size_t)NH];
                const float f3 = B[base + 3 * (size_t)NH];
                ushort4 b;
                b.x = f2bf(f0); b.y = f2bf(f1); b.z = f2bf(f2); b.w = f2bf(f3);
                *(ushort4*)(&lB[n * PITCH + ks]) = b;
            }
        }
        __syncthreads();

        const int mrow = wid * 16 + (lane & 15);
        #pragma unroll
        for (int ks = 0; ks < 2; ++ks) {
            const int koff = ks * 32 + ((lane >> 4) * 8);
            const bf16x8 af = *(const bf16x8*)(&lA[mrow * PITCH + koff]);
            #pragma unroll
            for (int nf = 0; nf < 4; ++nf) {
                const bf16x8 bfr = *(const bf16x8*)(&lB[(nf * 16 + (lane & 15)) * PITCH + koff]);
                acc[nf] = __builtin_amdgcn_mfma_f32_16x16x32_bf16(af, bfr, acc[nf], 0, 0, 0);
            }
        }
    }

    #pragma unroll
    for (int nf = 0; nf < 4; ++nf) {
        #pragma unroll
        for (int i = 0; i < 4; ++i) {
            const int row = wid * 16 + ((lane >> 4) * 4) + i;
            const int col = nf * 16 + (lane & 15);
            O[(size_t)row * NH + col] = acc[nf][i];
        }
    }
}

extern "C" void kernel_launch(void* const* d_in, const int* in_sizes, int n_in,
                              void* d_out, int out_size, void* d_ws, size_t ws_size,
                              hipStream_t stream) {
    const float* x  = (const float*)d_in[0];
    const float* w1 = (const float*)d_in[2];
    const float* w3 = (const float*)d_in[3];
    const float* w2 = (const float*)d_in[4];
    float* out = (float*)d_out;
    ushort* gated = (ushort*)d_ws;                         // 23.1 MB
    ushort* xbf   = (ushort*)((char*)d_ws + (32u << 20));  // 8.4 MB @ +32MB
    ushort* h1    = (ushort*)((char*)d_ws + (48u << 20));  // 23.1 MB @ +48MB

    xcast<<<dim3((TPE * NE * NH) / (256 * 8)), dim3(256), 0, stream>>>(x, xbf);

    dim3 g1(NF / 64, NE);    // (44, 64)
    k1_mm<0><<<g1, dim3(256), 0, stream>>>(xbf, w1, nullptr, h1);   // h1 = x@w1^T
    k1_mm<1><<<g1, dim3(256), 0, stream>>>(xbf, w3, h1, gated);     // gated = silu(h1)*(x@w3^T)

    dim3 g2(NH / 64, NE);    // (16, 64)
    k2_down<<<g2, dim3(256), 0, stream>>>(gated, w2, out);
}

// Round 13
// 469.845 us; speedup vs baseline: 1.3255x; 1.3255x over previous
//
#include <hip/hip_runtime.h>
#include <hip/hip_bf16.h>

#define NE   64
#define NH   1024
#define NF   2816
#define TPE  64
#define PITCH 72      // k2 LDS pitch (validated ~7 TB/s)
#define WP   1032     // w-panel pitch (ushorts): row stride 2064B -> 4-bank offset

typedef __attribute__((ext_vector_type(8))) short bf16x8;
typedef __attribute__((ext_vector_type(4))) float f32x4;

__device__ __forceinline__ ushort f2bf(float f) {
    union { float f; unsigned u; } v; v.f = f;
    unsigned r = v.u + 0x7fffu + ((v.u >> 16) & 1u);
    return (ushort)(r >> 16);
}

__device__ __forceinline__ float bf2f(ushort u) {
    union { unsigned u; float f; } v; v.u = ((unsigned)u) << 16;
    return v.f;
}

__device__ __forceinline__ bf16x8 cvt8(f32x4 lo, f32x4 hi) {
    bf16x8 r;
    #pragma unroll
    for (int j = 0; j < 4; ++j) {
        r[j]     = (short)f2bf(lo[j]);
        r[4 + j] = (short)f2bf(hi[j]);
    }
    return r;
}

// ---------------- Kernel 0: x (f32) -> xb (bf16), one pass -----------------
__global__ __launch_bounds__(256)
void xcast(const float* __restrict__ x, ushort* __restrict__ xb) {
    const int i = blockIdx.x * 256 + threadIdx.x;
    const f32x4 a = *(const f32x4*)(x + (size_t)i * 8);
    const f32x4 b = *(const f32x4*)(x + (size_t)i * 8 + 4);
    *(bf16x8*)(xb + (size_t)i * 8) = cvt8(a, b);
}

// ---- Kernel 1a/1b: D[f][t] = w-panel x x^T — one-visit forward weight stream
// Unconfounded row-locality test: (a) each 4KB weight row read ONCE, forward,
// 2KB/wave-instr; (b) MFMA loop 100% register/LDS (x = 32 B-frags in VGPRs,
// loaded once from L3-hot xb); (c) T14 issue-early staging, dbuf panels, one
// barrier/panel, ~16KB in flight per wave; (d) 4 panels of 16 f-rows per block.
// Output transposed: GATE=0 writes h1T[(e*NF+f)*64+t]; GATE=1 reads h1T,
// computes gated, transposes via LDS, writes gated NATURAL (k2 unchanged).
template <int GATE>
__global__ __launch_bounds__(256, 2)
void k1_mm(const ushort* __restrict__ xb,
           const float* __restrict__ w,
           const ushort* __restrict__ h1in,
           ushort* __restrict__ outp) {
    __shared__ ushort lW[2][16 * WP];   // 66 KB double-buffered panel
    __shared__ ushort lT[64 * 72];      // 9.2 KB transpose buffer (GATE=1)

    const int jt   = blockIdx.x;               // 64-f-row slab (0..43)
    const int e    = blockIdx.y;
    const int tid  = threadIdx.x;
    const int lane = tid & 63;
    const int wid  = tid >> 6;
    const int m15  = lane & 15;
    const int hi   = lane >> 4;
    const int tb   = wid * 16;                  // wave's token base

    const float* B = w + ((size_t)e * NF + (size_t)jt * 64) * NH;

    // x as MFMA B-operand fragments, loaded ONCE (L3-hot): lane n=m15 -> token
    const ushort* xrow = xb + ((size_t)e * TPE + tb + m15) * NH;
    bf16x8 xf[32];
    #pragma unroll
    for (int kk = 0; kk < 32; ++kk)
        xf[kk] = *(const bf16x8*)(xrow + kk * 32 + hi * 8);

    f32x4 v[16];
    // issue 16 dwordx4 for panel p (16 rows x 4KB, forward-contiguous)
    #define K1_ISSUE(p)                                                          \
        do {                                                                     \
            _Pragma("unroll")                                                    \
            for (int s = 0; s < 8; ++s) {                                        \
                const int S    = s * 256 + tid;                                  \
                const int row  = S >> 7;                                         \
                const int colp = S & 127;                                        \
                const float* src = B + (size_t)((p) * 16 + row) * NH + colp * 8; \
                v[2 * s]     = *(const f32x4*)src;                               \
                v[2 * s + 1] = *(const f32x4*)(src + 4);                         \
            }                                                                    \
        } while (0)
    #define K1_WRITE(b)                                                          \
        do {                                                                     \
            _Pragma("unroll")                                                    \
            for (int s = 0; s < 8; ++s) {                                        \
                const int S    = s * 256 + tid;                                  \
                const int row  = S >> 7;                                         \
                const int colp = S & 127;                                        \
                *(bf16x8*)(&lW[b][row * WP + colp * 8]) =                        \
                    cvt8(v[2 * s], v[2 * s + 1]);                                \
            }                                                                    \
        } while (0)

    K1_ISSUE(0); K1_WRITE(0);
    __syncthreads();

    #pragma unroll
    for (int p = 0; p < 4; ++p) {
        if (p < 3) K1_ISSUE(p + 1);             // in flight through compute

        f32x4 acc = f32x4{0.f, 0.f, 0.f, 0.f};
        const ushort* pw = lW[p & 1];
        #pragma unroll
        for (int kk = 0; kk < 32; ++kk) {       // A=w (lane m=m15=f-row)
            const bf16x8 wf = *(const bf16x8*)(pw + m15 * WP + kk * 32 + hi * 8);
            acc = __builtin_amdgcn_mfma_f32_16x16x32_bf16(wf, xf[kk], acc, 0, 0, 0);
        }

        if (p < 3) K1_WRITE((p + 1) & 1);       // buffer freed by prev barrier

        // epilogue: D row=f=hi*4+i, col=token=m15
        #pragma unroll
        for (int i = 0; i < 4; ++i) {
            const int f_loc = p * 16 + hi * 4 + i;           // 0..63 in slab
            if (GATE) {
                const size_t hidx = ((size_t)e * NF + jt * 64 + f_loc) * 64 + tb + m15;
                const float h1v = bf2f(h1in[hidx]);
                const float s   = (h1v / (1.f + __expf(-h1v))) * acc[i];
                lT[(tb + m15) * 72 + f_loc] = f2bf(s);
            } else {
                outp[((size_t)e * NF + jt * 64 + f_loc) * 64 + tb + m15] = f2bf(acc[i]);
            }
        }
        __syncthreads();
    }
    #undef K1_ISSUE
    #undef K1_WRITE

    if (GATE) {   // coalesced natural-layout write of gated (k2 unchanged)
        #pragma unroll
        for (int s = 0; s < 2; ++s) {
            const int S  = s * 256 + tid;
            const int t  = S >> 3;
            const int c8 = (S & 7) * 8;
            *(bf16x8*)(&outp[((size_t)e * TPE + t) * NF + jt * 64 + c8]) =
                *(const bf16x8*)(&lT[t * 72 + c8]);
        }
    }
}

// ---------------- Kernel 2: out = gated @ w2 (per expert), fp32 out ------------
// (unchanged — co-swept weight rows at ~7 TB/s; at roofline)
__global__ __launch_bounds__(256, 2)
void k2_down(const ushort* __restrict__ g,
             const float* __restrict__ w2,
             float* __restrict__ out) {
    __shared__ ushort lA[64 * PITCH];
    __shared__ ushort lB[64 * PITCH];

    const int jt   = blockIdx.x;
    const int e    = blockIdx.y;
    const int tid  = threadIdx.x;
    const int lane = tid & 63;
    const int wid  = tid >> 6;

    const ushort* A = g  + (size_t)e * TPE * NF;
    const float*  B = w2 + (size_t)e * NF * NH + (size_t)jt * 64;
    float* O = out + (size_t)e * TPE * NH + (size_t)jt * 64;

    f32x4 acc[4];
    for (int nf = 0; nf < 4; ++nf) acc[nf] = f32x4{0.f, 0.f, 0.f, 0.f};

    for (int kt = 0; kt < NF / 64; ++kt) {
        __syncthreads();
        #pragma unroll
        for (int r = 0; r < 2; ++r) {
            const int q   = tid + r * 256;
            const int row = q >> 3;
            const int k8  = (q & 7) * 8;
            *(bf16x8*)(&lA[row * PITCH + k8]) =
                *(const bf16x8*)(A + (size_t)row * NF + kt * 64 + k8);
        }
        {
            const int n  = tid & 63;
            const int kq = (tid >> 6) * 4;
            #pragma unroll
            for (int r = 0; r < 4; ++r) {
                const int ks = kq + r * 16;
                const size_t base = (size_t)(kt * 64 + ks) * NH + n;
                const float f0 = B[base];
                const float f1 = B[base + NH];
                const float f2 = B[base + 2 * (size_t)NH];
                const float f3 = B[base + 3 * (size_t)NH];
                ushort4 b;
                b.x = f2bf(f0); b.y = f2bf(f1); b.z = f2bf(f2); b.w = f2bf(f3);
                *(ushort4*)(&lB[n * PITCH + ks]) = b;
            }
        }
        __syncthreads();

        const int mrow = wid * 16 + (lane & 15);
        #pragma unroll
        for (int ks = 0; ks < 2; ++ks) {
            const int koff = ks * 32 + ((lane >> 4) * 8);
            const bf16x8 af = *(const bf16x8*)(&lA[mrow * PITCH + koff]);
            #pragma unroll
            for (int nf = 0; nf < 4; ++nf) {
                const bf16x8 bfr = *(const bf16x8*)(&lB[(nf * 16 + (lane & 15)) * PITCH + koff]);
                acc[nf] = __builtin_amdgcn_mfma_f32_16x16x32_bf16(af, bfr, acc[nf], 0, 0, 0);
            }
        }
    }

    #pragma unroll
    for (int nf = 0; nf < 4; ++nf) {
        #pragma unroll
        for (int i = 0; i < 4; ++i) {
            const int row = wid * 16 + ((lane >> 4) * 4) + i;
            const int col = nf * 16 + (lane & 15);
            O[(size_t)row * NH + col] = acc[nf][i];
        }
    }
}

extern "C" void kernel_launch(void* const* d_in, const int* in_sizes, int n_in,
                              void* d_out, int out_size, void* d_ws, size_t ws_size,
                              hipStream_t stream) {
    const float* x  = (const float*)d_in[0];
    const float* w1 = (const float*)d_in[2];
    const float* w3 = (const float*)d_in[3];
    const float* w2 = (const float*)d_in[4];
    float* out = (float*)d_out;
    ushort* gated = (ushort*)d_ws;                         // 23.1 MB (natural)
    ushort* xbf   = (ushort*)((char*)d_ws + (32u << 20));  // 8.4 MB
    ushort* h1T   = (ushort*)((char*)d_ws + (48u << 20));  // 23.1 MB (transposed)

    xcast<<<dim3((TPE * NE * NH) / (256 * 8)), dim3(256), 0, stream>>>(x, xbf);

    dim3 g1(NF / 64, NE);    // (44, 64)
    k1_mm<0><<<g1, dim3(256), 0, stream>>>(xbf, w1, nullptr, h1T);
    k1_mm<1><<<g1, dim3(256), 0, stream>>>(xbf, w3, h1T, gated);

    dim3 g2(NH / 64, NE);    // (16, 64)
    k2_down<<<g2, dim3(256), 0, stream>>>(gated, w2, out);
}

// Round 14
// 447.976 us; speedup vs baseline: 1.3902x; 1.0488x over previous
//
#include <hip/hip_runtime.h>
#include <hip/hip_bf16.h>

#define NE   64
#define NH   1024
#define NF   2816
#define TPE  64
#define PITCH 72      // k2 LDS pitch (unchanged, validated)
#define K1BUF 10240   // floats per k1 buffer: x-bf16 8KB + w1 16KB + w3 16KB = 40KB

typedef __attribute__((ext_vector_type(8))) short bf16x8;
typedef __attribute__((ext_vector_type(4))) float f32x4;

__device__ __forceinline__ ushort f2bf(float f) {
    union { float f; unsigned u; } v; v.f = f;
    unsigned r = v.u + 0x7fffu + ((v.u >> 16) & 1u);
    return (ushort)(r >> 16);
}

__device__ __forceinline__ bf16x8 cvt8(f32x4 lo, f32x4 hi) {
    bf16x8 r;
    #pragma unroll
    for (int j = 0; j < 4; ++j) {
        r[j]     = (short)f2bf(lo[j]);
        r[4 + j] = (short)f2bf(hi[j]);
    }
    return r;
}

#define GLOAD16(gsrc, ldst)                                                          \
    __builtin_amdgcn_global_load_lds(                                                \
        (const __attribute__((address_space(1))) void*)(gsrc),                       \
        (__attribute__((address_space(3))) void*)(ldst), 16, 0, 0)

// ---------------- Kernel 0: x (f32) -> xb (bf16), one pass -----------------
__global__ __launch_bounds__(256)
void xcast(const float* __restrict__ x, ushort* __restrict__ xb) {
    const int i = blockIdx.x * 256 + threadIdx.x;   // 8 elems per thread
    const f32x4 a = *(const f32x4*)(x + (size_t)i * 8);
    const f32x4 b = *(const f32x4*)(x + (size_t)i * 8 + 4);
    *(bf16x8*)(xb + (size_t)i * 8) = cvt8(a, b);
}

// ---------------- Kernel 1: gated = silu(x@w1^T) * (x@w3^T), bf16 out ----------
// grid: (NF/64, NE) = (44, 64) jt-major. block 256 (4 waves). M=64 x N=64,
// BK=64, 16 K-steps. DOUBLE-BUFFERED gload_lds pipeline with counted vmcnt
// (T4): one full tile (10 loads/wave) always in flight; s_waitcnt vmcnt(10)
// in steady state, vmcnt(0) only on the last iteration. Raw s_barriers.
// Source pre-swizzle (rule 21): x rows (8 slots) slot'=c^(row&7);
// w rows (16 slots) slot'=c^(row&15). Read side probes the same involution.
// [R6 best-measured config: 436.7 us total; at the pattern-constrained
//  roofline — fused k1 weight streams pin at ~4.5 TB/s across all 12
//  structures tried; see R13 post-mortem.]
__global__ __launch_bounds__(256, 2)
void k1_gate(const ushort* __restrict__ xb,
             const float* __restrict__ w1,
             const float* __restrict__ w3,
             ushort* __restrict__ g) {
    __shared__ float fbuf[2 * K1BUF];   // 80 KB -> 2 blocks/CU

    const int jt   = blockIdx.x;               // ff 64-tile (0..43)
    const int e    = blockIdx.y;               // expert
    const int tid  = threadIdx.x;
    const int lane = tid & 63;
    const int wid  = tid >> 6;
    const int m15  = lane & 15;
    const int hi   = lane >> 4;
    const int mrow = wid * 16 + m15;

    const ushort* xA = xb + (size_t)e * TPE * NH;
    const float*  B1 = w1 + ((size_t)e * NF + (size_t)jt * 64) * NH;
    const float*  B3 = w3 + ((size_t)e * NF + (size_t)jt * 64) * NH;

    f32x4 acc1[4], acc3[4];
    #pragma unroll
    for (int nf = 0; nf < 4; ++nf) {
        acc1[nf] = f32x4{0.f, 0.f, 0.f, 0.f};
        acc3[nf] = f32x4{0.f, 0.f, 0.f, 0.f};
    }

    // stage tile t into buffer b (10 gload_lds per thread)
    #define STAGE(t, b)                                                              \
        do {                                                                         \
            float* bb = fbuf + (b) * K1BUF;                                          \
            ushort* sX = (ushort*)bb;                                                \
            float*  sW1 = bb + 2048;                                                 \
            float*  sW3 = bb + 6144;                                                 \
            const size_t kb = (size_t)(t) * 64;                                      \
            _Pragma("unroll")                                                        \
            for (int i = 0; i < 2; ++i) {                                            \
                const int S   = i * 256 + tid;                                       \
                const int row = S >> 3;                                              \
                const int cs  = (S & 7) ^ (row & 7);                                 \
                GLOAD16(xA + (size_t)row * NH + kb + cs * 8, sX + (S & ~63) * 8);    \
            }                                                                        \
            _Pragma("unroll")                                                        \
            for (int i = 0; i < 4; ++i) {                                            \
                const int S   = i * 256 + tid;                                       \
                const int row = S >> 4;                                              \
                const int cs  = (S & 15) ^ (row & 15);                               \
                const size_t goff = (size_t)row * NH + kb + cs * 4;                  \
                GLOAD16(B1 + goff, sW1 + (S & ~63) * 4);                             \
                GLOAD16(B3 + goff, sW3 + (S & ~63) * 4);                             \
            }                                                                        \
        } while (0)

    // prologue: two tiles in flight
    STAGE(0, 0);
    STAGE(1, 1);

    #pragma unroll
    for (int kt = 0; kt < 16; ++kt) {
        // wait: tile kt landed (in-order retire); tile kt+1's 10 still in flight
        if (kt < 15) asm volatile("s_waitcnt vmcnt(10)" ::: "memory");
        else         asm volatile("s_waitcnt vmcnt(0)"  ::: "memory");
        __builtin_amdgcn_s_barrier();          // everyone's tile-kt data in LDS
        asm volatile("" ::: "memory");

        const float* bb = fbuf + (kt & 1) * K1BUF;
        const ushort* sX = (const ushort*)bb;
        const float*  sW1 = bb + 2048;
        const float*  sW3 = bb + 6144;

        #pragma unroll
        for (int ks = 0; ks < 2; ++ks) {
            const int sxa = ((ks * 4 + hi) ^ (mrow & 7)) << 3;
            const bf16x8 af = *(const bf16x8*)(sX + mrow * 64 + sxa);
            const int c0 = ks * 8 + hi * 2;
            #pragma unroll
            for (int nf = 0; nf < 4; ++nf) {
                const int brow = nf * 16 + m15;     // brow&15 == m15
                const int sa0 = (c0 ^ m15) << 2, sa1 = ((c0 + 1) ^ m15) << 2;
                const f32x4 p0 = *(const f32x4*)&sW1[brow * 64 + sa0];
                const f32x4 p1 = *(const f32x4*)&sW1[brow * 64 + sa1];
                acc1[nf] = __builtin_amdgcn_mfma_f32_16x16x32_bf16(af, cvt8(p0, p1), acc1[nf], 0, 0, 0);
                const f32x4 q0 = *(const f32x4*)&sW3[brow * 64 + sa0];
                const f32x4 q1 = *(const f32x4*)&sW3[brow * 64 + sa1];
                acc3[nf] = __builtin_amdgcn_mfma_f32_16x16x32_bf16(af, cvt8(q0, q1), acc3[nf], 0, 0, 0);
            }
        }

        asm volatile("" ::: "memory");
        __builtin_amdgcn_s_barrier();          // all waves done reading buf[kt&1]
        asm volatile("" ::: "memory");
        if (kt + 2 < 16) STAGE(kt + 2, kt & 1);  // refill the buffer just read
    }
    #undef STAGE

    // epilogue: SwiGLU, bf16 gated. C/D layout: col=lane&15, row=(lane>>4)*4+i
    #pragma unroll
    for (int nf = 0; nf < 4; ++nf) {
        #pragma unroll
        for (int i = 0; i < 4; ++i) {
            const float h1v = acc1[nf][i];
            const float h3v = acc3[nf][i];
            const float s   = (h1v / (1.f + __expf(-h1v))) * h3v;
            const int row = wid * 16 + (hi * 4) + i;
            const int col = jt * 64 + nf * 16 + m15;
            const size_t t = (size_t)e * TPE + row;
            g[t * NF + col] = f2bf(s);
        }
    }
}

// ---------------- Kernel 2: out = gated @ w2 (per expert), fp32 out ------------
// (unchanged — measured ~104 us at ~7.1 TB/s on w2; at roofline)
__global__ __launch_bounds__(256, 2)
void k2_down(const ushort* __restrict__ g,
             const float* __restrict__ w2,
             float* __restrict__ out) {
    __shared__ ushort lA[64 * PITCH];
    __shared__ ushort lB[64 * PITCH];

    const int jt   = blockIdx.x;
    const int e    = blockIdx.y;
    const int tid  = threadIdx.x;
    const int lane = tid & 63;
    const int wid  = tid >> 6;

    const ushort* A = g  + (size_t)e * TPE * NF;
    const float*  B = w2 + (size_t)e * NF * NH + (size_t)jt * 64;
    float* O = out + (size_t)e * TPE * NH + (size_t)jt * 64;

    f32x4 acc[4];
    for (int nf = 0; nf < 4; ++nf) acc[nf] = f32x4{0.f, 0.f, 0.f, 0.f};

    for (int kt = 0; kt < NF / 64; ++kt) {   // 44 iters
        __syncthreads();
        #pragma unroll
        for (int r = 0; r < 2; ++r) {
            const int q   = tid + r * 256;
            const int row = q >> 3;
            const int k8  = (q & 7) * 8;
            *(bf16x8*)(&lA[row * PITCH + k8]) =
                *(const bf16x8*)(A + (size_t)row * NF + kt * 64 + k8);
        }
        {
            const int n  = tid & 63;
            const int kq = (tid >> 6) * 4;
            #pragma unroll
            for (int r = 0; r < 4; ++r) {
                const int ks = kq + r * 16;
                const size_t base = (size_t)(kt * 64 + ks) * NH + n;
                const float f0 = B[base];
                const float f1 = B[base + NH];
                const float f2 = B[base + 2 * (size_t)NH];
                const float f3 = B[base + 3 * (size_t)NH];
                ushort4 b;
                b.x = f2bf(f0); b.y = f2bf(f1); b.z = f2bf(f2); b.w = f2bf(f3);
                *(ushort4*)(&lB[n * PITCH + ks]) = b;
            }
        }
        __syncthreads();

        const int mrow = wid * 16 + (lane & 15);
        #pragma unroll
        for (int ks = 0; ks < 2; ++ks) {
            const int koff = ks * 32 + ((lane >> 4) * 8);
            const bf16x8 af = *(const bf16x8*)(&lA[mrow * PITCH + koff]);
            #pragma unroll
            for (int nf = 0; nf < 4; ++nf) {
                const bf16x8 bfr = *(const bf16x8*)(&lB[(nf * 16 + (lane & 15)) * PITCH + koff]);
                acc[nf] = __builtin_amdgcn_mfma_f32_16x16x32_bf16(af, bfr, acc[nf], 0, 0, 0);
            }
        }
    }

    #pragma unroll
    for (int nf = 0; nf < 4; ++nf) {
        #pragma unroll
        for (int i = 0; i < 4; ++i) {
            const int row = wid * 16 + ((lane >> 4) * 4) + i;
            const int col = nf * 16 + (lane & 15);
            O[(size_t)row * NH + col] = acc[nf][i];
        }
    }
}

extern "C" void kernel_launch(void* const* d_in, const int* in_sizes, int n_in,
                              void* d_out, int out_size, void* d_ws, size_t ws_size,
                              hipStream_t stream) {
    const float* x  = (const float*)d_in[0];
    const float* w1 = (const float*)d_in[2];
    const float* w3 = (const float*)d_in[3];
    const float* w2 = (const float*)d_in[4];
    float* out = (float*)d_out;
    ushort* gated = (ushort*)d_ws;                         // 23.1 MB
    ushort* xbf   = (ushort*)((char*)d_ws + (32u << 20));  // 8.4 MB @ +32MB

    xcast<<<dim3((TPE * NE * NH) / (256 * 8)), dim3(256), 0, stream>>>(x, xbf);

    dim3 g1(NF / 64, NE);    // (44, 64) jt-major
    k1_gate<<<g1, dim3(256), 0, stream>>>(xbf, w1, w3, gated);

    dim3 g2(NH / 64, NE);    // (16, 64)
    k2_down<<<g2, dim3(256), 0, stream>>>(gated, w2, out);
}